// Round 16
// baseline (60.110 us; speedup 1.0000x reference)
//
#include <hip/hip_runtime.h>

#define DMODEL 1024
#define DHEAD 128
#define CHUNK 128
#define NCHUNK 32

typedef __attribute__((ext_vector_type(4))) float f32x4;
typedef __attribute__((ext_vector_type(8))) short bf16x8;

__device__ __forceinline__ unsigned short f2bf(float f) {
  union { float f; unsigned u; } v; v.f = f;
  unsigned r = v.u + 0x7FFF + ((v.u >> 16) & 1);   // RNE
  return (unsigned short)(r >> 16);
}
__device__ __forceinline__ float bf2f(unsigned short h) {
  union { unsigned u; float f; } v; v.u = ((unsigned)h) << 16;
  return v.f;
}
__device__ __forceinline__ unsigned cvtpk(float lo, float hi) {
  unsigned r;
  asm("v_cvt_pk_bf16_f32 %0, %1, %2" : "=v"(r) : "v"(lo), "v"(hi));
  return r;
}
__device__ __forceinline__ void gload16(const void* g, void* l) {
  __builtin_amdgcn_global_load_lds(
      (const __attribute__((address_space(1))) unsigned int*)g,
      (__attribute__((address_space(3))) unsigned int*)l, 16, 0, 0);
}

// ---------------- K0: W -> W^T bf16 [which][n][k] ----------------
__global__ __launch_bounds__(256) void transpose_w_kernel(
    const float* __restrict__ Wq, const float* __restrict__ Wk,
    const float* __restrict__ Wv, unsigned short* __restrict__ WT) {
  int id = blockIdx.x * 256 + threadIdx.x;
  int w = id >> 17;
  int rem = id & 131071;
  int n = rem >> 10;
  int k = rem & 1023;
  const float* W = (w == 0) ? Wq : (w == 1) ? Wk : Wv;
  WT[id] = f2bf(W[(size_t)k * DHEAD + n]);
}

// ---------------- K1: projection GEMM + phi (R7 structure, n-split 2) ----------------
// grid (256, 6): y = which*2 + nh. BM=64, BN=64, BK=64, 128 threads (2 waves).
// LDS 24 KB -> 6 blocks/CU resident; plain 2-barrier K-loop (best measured/unit).
__global__ __launch_bounds__(128) void proj_kernel(
    const float* __restrict__ x, const unsigned short* __restrict__ WT,
    unsigned short* __restrict__ phiQ, unsigned short* __restrict__ phiK,
    unsigned short* __restrict__ Vb) {
  const int which = blockIdx.y >> 1;
  const int nh = blockIdx.y & 1;
  const int n0 = nh << 6;
  const unsigned short* Wt = WT + (size_t)which * (DHEAD * DMODEL);
  unsigned short* outp = (which == 0) ? phiQ : (which == 1) ? phiK : Vb;
  const int m0 = blockIdx.x * 64;

  __shared__ float xs[64][64];             // 16 KB, 256B rows = 16 slots, swizzled
  __shared__ unsigned short ws[64][64];    // 8 KB, 128B rows = 8 slots, swizzled

  const int tid = threadIdx.x;
  const int wave = tid >> 6;               // 0..1
  const int lane = tid & 63;
  const int lrow = lane & 15, kgrp = lane >> 4;

  f32x4 acc[2][4];
#pragma unroll
  for (int i = 0; i < 2; ++i)
#pragma unroll
    for (int j = 0; j < 4; ++j) acc[i][j] = (f32x4)0.0f;

  for (int kk = 0; kk < DMODEL; kk += 64) {
    if (kk) __syncthreads();               // prior readers done
    // stage x tile 64x64 fp32 via global_load_lds, source pre-swizzled
#pragma unroll
    for (int i = 0; i < 8; ++i) {
      int instr = i * 2 + wave;
      int row = instr * 4 + (lane >> 4);
      int slot = lane & 15;
      int gcol = (slot ^ (row & 7)) << 2;
      gload16(&x[(size_t)(m0 + row) * DMODEL + kk + gcol],
              (char*)xs + instr * 1024);
    }
    // stage W^T tile 64x64 bf16
#pragma unroll
    for (int i = 0; i < 4; ++i) {
      int instr = i * 2 + wave;
      int row = instr * 8 + (lane >> 3);
      int slot = lane & 7;
      int gcol = (slot ^ (row & 7)) << 3;
      gload16(&Wt[(size_t)(n0 + row) * DMODEL + kk + gcol],
              (char*)ws + instr * 1024);
    }
    __syncthreads();                       // drain -> tiles ready

#pragma unroll
    for (int ks2 = 0; ks2 < 2; ++ks2) {
      bf16x8 af[2];
#pragma unroll
      for (int mr = 0; mr < 2; ++mr) {
        int arow = wave * 32 + mr * 16 + lrow;
        int s0 = ks2 * 8 + kgrp * 2;
        const float4 f0 = *reinterpret_cast<const float4*>(
            &xs[arow][(s0 ^ (arow & 7)) << 2]);
        const float4 f1 = *reinterpret_cast<const float4*>(
            &xs[arow][((s0 + 1) ^ (arow & 7)) << 2]);
        union { unsigned u[4]; bf16x8 v; } p;
        p.u[0] = cvtpk(f0.x, f0.y);
        p.u[1] = cvtpk(f0.z, f0.w);
        p.u[2] = cvtpk(f1.x, f1.y);
        p.u[3] = cvtpk(f1.z, f1.w);
        af[mr] = p.v;
      }
#pragma unroll
      for (int nt = 0; nt < 4; ++nt) {
        int brow = nt * 16 + lrow;
        int bs = ks2 * 4 + kgrp;
        bf16x8 bf = *reinterpret_cast<const bf16x8*>(
            &ws[brow][(bs ^ (brow & 7)) << 3]);
        acc[0][nt] = __builtin_amdgcn_mfma_f32_16x16x32_bf16(af[0], bf, acc[0][nt], 0, 0, 0);
        acc[1][nt] = __builtin_amdgcn_mfma_f32_16x16x32_bf16(af[1], bf, acc[1][nt], 0, 0, 0);
      }
    }
  }
  // epilogue: phi for q/k, plain for v; store bf16
#pragma unroll
  for (int mr = 0; mr < 2; ++mr)
#pragma unroll
    for (int nt = 0; nt < 4; ++nt)
#pragma unroll
      for (int r = 0; r < 4; ++r) {
        int row = m0 + wave * 32 + mr * 16 + kgrp * 4 + r;
        int col = n0 + nt * 16 + lrow;
        float v = acc[mr][nt][r];
        if (which < 2) v = (v > 0.0f) ? (v + 1.0f) : __expf(v);
        outp[(size_t)row * DHEAD + col] = f2bf(v);
      }
}

// ---------------- K2: per-chunk KV^T = v^T @ k (dv-split), ks colsums ----------------
__global__ __launch_bounds__(256) void chunkkv_kernel(
    const unsigned short* __restrict__ phiK, const unsigned short* __restrict__ Vb,
    float* __restrict__ KVc, float* __restrict__ ksc) {
  const int c = blockIdx.x;
  const int yv = blockIdx.y;
  const size_t base = (size_t)c * CHUNK * DHEAD;
  __shared__ unsigned short kt[128][136];   // k^T [d][t] (full)
  __shared__ unsigned short vt[64][136];    // v^T rows yv*64..+64
  __shared__ float csum[2][128];
  const int tid = threadIdx.x;
  const int wave = tid >> 6, lane = tid & 63;
  const int lrow = lane & 15, kgrp = lane >> 4;

  {
    int t = tid & 127, dp = tid >> 7;
#pragma unroll
    for (int i = 0; i < 8; ++i) {
      int d0 = (dp + 2 * i) * 8;
      uint4 k4 = *reinterpret_cast<const uint4*>(&phiK[base + (size_t)t * DHEAD + d0]);
      const unsigned short* kp = reinterpret_cast<const unsigned short*>(&k4);
#pragma unroll
      for (int j = 0; j < 8; ++j) kt[d0 + j][t] = kp[j];
    }
#pragma unroll
    for (int i = 0; i < 4; ++i) {
      int dl = (dp + 2 * i) * 8;             // 0..63 local dv
      uint4 v4 = *reinterpret_cast<const uint4*>(
          &Vb[base + (size_t)t * DHEAD + yv * 64 + dl]);
      const unsigned short* vp = reinterpret_cast<const unsigned short*>(&v4);
#pragma unroll
      for (int j = 0; j < 8; ++j) vt[dl + j][t] = vp[j];
    }
  }
  __syncthreads();

  f32x4 acc[8];
#pragma unroll
  for (int j = 0; j < 8; ++j) acc[j] = (f32x4)0.0f;
#pragma unroll
  for (int ks = 0; ks < 4; ++ks) {
    int t0 = ks * 32 + kgrp * 8;
    bf16x8 afrag = *reinterpret_cast<const bf16x8*>(&vt[wave * 16 + lrow][t0]);
#pragma unroll
    for (int tc = 0; tc < 8; ++tc) {
      bf16x8 bfrag = *reinterpret_cast<const bf16x8*>(&kt[tc * 16 + lrow][t0]);
      acc[tc] = __builtin_amdgcn_mfma_f32_16x16x32_bf16(afrag, bfrag, acc[tc], 0, 0, 0);
    }
  }
  float* KVout = KVc + (size_t)c * (DHEAD * DHEAD);   // [dv][d]
#pragma unroll
  for (int tc = 0; tc < 8; ++tc)
#pragma unroll
    for (int r = 0; r < 4; ++r) {
      int dv = yv * 64 + wave * 16 + kgrp * 4 + r;
      int d = tc * 16 + lrow;
      KVout[dv * DHEAD + d] = acc[tc][r];
    }
  if (yv == 0) {
    int d = tid & 127, hh = tid >> 7;
    float s = 0.0f;
    for (int t = hh * 64; t < hh * 64 + 64; ++t) s += bf2f(kt[d][t]);
    csum[hh][d] = s;
    __syncthreads();
    if (tid < 128) ksc[(size_t)c * DHEAD + tid] = csum[0][tid] + csum[1][tid];
  }
}

// ---------------- K3: exclusive prefix over chunks ----------------
__global__ __launch_bounds__(256) void prefix_kernel(
    const float* __restrict__ KVc, const float* __restrict__ ksc,
    unsigned short* __restrict__ KVp, float* __restrict__ ksp) {
  if (blockIdx.x < 256) {
    int id = blockIdx.x * 256 + threadIdx.x;
    int b = id >> 14;
    int e = id & 16383;
    size_t base = (size_t)b * NCHUNK * 16384 + e;
    float acc = 0.0f;
    for (int c = 0; c < NCHUNK; ++c) {
      KVp[base + (size_t)c * 16384] = f2bf(acc);
      acc += KVc[base + (size_t)c * 16384];
    }
  } else {
    for (int i = threadIdx.x; i < 512; i += 256) {
      int b = i >> 7, d = i & 127;
      size_t base = (size_t)b * NCHUNK * DHEAD + d;
      float acc = 0.0f;
      for (int c = 0; c < NCHUNK; ++c) {
        ksp[base + (size_t)c * DHEAD] = acc;
        acc += ksc[base + (size_t)c * DHEAD];
      }
    }
  }
}

// ---------------- K4: per-chunk output, split in q-row halves ----------------
__global__ __launch_bounds__(256) void out_kernel(
    const unsigned short* __restrict__ phiQ, const unsigned short* __restrict__ phiK,
    const unsigned short* __restrict__ Vb, const unsigned short* __restrict__ KVp,
    const float* __restrict__ ksp, float* __restrict__ outp) {
  const int c = blockIdx.x;
  const int h = blockIdx.y;
  const size_t kvbase = (size_t)c * CHUNK * DHEAD;
  const size_t qbase = kvbase + (size_t)h * 64 * DHEAD;
  __shared__ unsigned short qb[64][136];
  __shared__ unsigned short kb[128][136];
  __shared__ unsigned short vt[128][136];
  __shared__ float dsum[4][64];
  __shared__ float ks_l[128];
  const int tid = threadIdx.x;
  const int wave = tid >> 6, lane = tid & 63;
  const int lrow = lane & 15, kgrp = lane >> 4;

#pragma unroll
  for (int it = 0; it < 4; ++it) {
    int idx = it * 256 + tid;
    int t = idx >> 4;
    int d0 = (idx & 15) << 3;
    *reinterpret_cast<uint4*>(&qb[t][d0]) =
        *reinterpret_cast<const uint4*>(&phiQ[qbase + (size_t)t * DHEAD + d0]);
  }
  if (tid < 128) ks_l[tid] = ksp[(size_t)c * DHEAD + tid];
  if (h == 0) {
#pragma unroll
    for (int it = 0; it < 4; ++it) {
      int idx = it * 256 + tid;
      int t = idx >> 4;
      int d0 = (idx & 15) << 3;
      *reinterpret_cast<uint4*>(&kb[t][d0]) =
          *reinterpret_cast<const uint4*>(&phiK[kvbase + (size_t)t * DHEAD + d0]);
    }
    int t = tid & 63, dp = tid >> 6;
#pragma unroll
    for (int i = 0; i < 4; ++i) {
      int d0 = (dp + 4 * i) * 8;
      uint4 v4 = *reinterpret_cast<const uint4*>(&Vb[kvbase + (size_t)t * DHEAD + d0]);
      const unsigned short* vp = reinterpret_cast<const unsigned short*>(&v4);
#pragma unroll
      for (int j = 0; j < 8; ++j) vt[d0 + j][t] = vp[j];
    }
  } else {
#pragma unroll
    for (int it = 0; it < 8; ++it) {
      int idx = it * 256 + tid;
      int t = idx >> 4;
      int d0 = (idx & 15) << 3;
      *reinterpret_cast<uint4*>(&kb[t][d0]) =
          *reinterpret_cast<const uint4*>(&phiK[kvbase + (size_t)t * DHEAD + d0]);
    }
    int t = tid & 127, dp = tid >> 7;
#pragma unroll
    for (int i = 0; i < 8; ++i) {
      int d0 = (dp + 2 * i) * 8;
      uint4 v4 = *reinterpret_cast<const uint4*>(&Vb[kvbase + (size_t)t * DHEAD + d0]);
      const unsigned short* vp = reinterpret_cast<const unsigned short*>(&v4);
#pragma unroll
      for (int j = 0; j < 8; ++j) vt[d0 + j][t] = vp[j];
    }
  }
  __syncthreads();

  if (h == 0) {
    f32x4 sa[4];
#pragma unroll
    for (int i = 0; i < 4; ++i) sa[i] = (f32x4)0.0f;
#pragma unroll
    for (int ks = 0; ks < 4; ++ks) {
      int d0 = ks * 32 + kgrp * 8;
      bf16x8 af = *reinterpret_cast<const bf16x8*>(&qb[wave * 16 + lrow][d0]);
#pragma unroll
      for (int tc = 0; tc < 4; ++tc) {
        bf16x8 bf = *reinterpret_cast<const bf16x8*>(&kb[tc * 16 + lrow][d0]);
        sa[tc] = __builtin_amdgcn_mfma_f32_16x16x32_bf16(af, bf, sa[tc], 0, 0, 0);
      }
    }
    __syncthreads();
#pragma unroll
    for (int tc = 0; tc < 4; ++tc)
#pragma unroll
      for (int r = 0; r < 4; ++r) {
        int trow = wave * 16 + kgrp * 4 + r;
        int s = tc * 16 + lrow;
        kb[trow][s] = f2bf((s <= trow) ? sa[tc][r] : 0.0f);
      }
  } else {
    f32x4 sa[8];
#pragma unroll
    for (int i = 0; i < 8; ++i) sa[i] = (f32x4)0.0f;
#pragma unroll
    for (int ks = 0; ks < 4; ++ks) {
      int d0 = ks * 32 + kgrp * 8;
      bf16x8 af = *reinterpret_cast<const bf16x8*>(&qb[wave * 16 + lrow][d0]);
#pragma unroll
      for (int tc = 0; tc < 8; ++tc) {
        bf16x8 bf = *reinterpret_cast<const bf16x8*>(&kb[tc * 16 + lrow][d0]);
        sa[tc] = __builtin_amdgcn_mfma_f32_16x16x32_bf16(af, bf, sa[tc], 0, 0, 0);
      }
    }
    __syncthreads();
#pragma unroll
    for (int tc = 0; tc < 8; ++tc)
#pragma unroll
      for (int r = 0; r < 4; ++r) {
        int trow = wave * 16 + kgrp * 4 + r;
        int s = tc * 16 + lrow;
        kb[trow][s] = f2bf((s <= 64 + trow) ? sa[tc][r] : 0.0f);
      }
  }
  __syncthreads();   // P visible

  {
    int t = tid & 63, h4 = tid >> 6;
    float s = 0.0f;
    if (h4 < 2) {
      if (h4 == 0 || h == 1) {
        for (int j = h4 * 64; j < h4 * 64 + 64; ++j) s += bf2f(kb[t][j]);
      }
    } else {
      for (int j = (h4 - 2) * 64; j < (h4 - 2) * 64 + 64; ++j)
        s += bf2f(qb[t][j]) * ks_l[j];
    }
    dsum[h4][t] = s;
  }

  f32x4 acc[8];
#pragma unroll
  for (int i = 0; i < 8; ++i) acc[i] = (f32x4)0.0f;
  {
    const int nks = (h == 0) ? 2 : 4;
    for (int ks = 0; ks < nks; ++ks) {
      int t0 = ks * 32 + kgrp * 8;
      bf16x8 af = *reinterpret_cast<const bf16x8*>(&kb[wave * 16 + lrow][t0]);
#pragma unroll
      for (int tc = 0; tc < 8; ++tc) {
        bf16x8 bf = *reinterpret_cast<const bf16x8*>(&vt[tc * 16 + lrow][t0]);
        acc[tc] = __builtin_amdgcn_mfma_f32_16x16x32_bf16(af, bf, acc[tc], 0, 0, 0);
      }
    }
  }
  __syncthreads();

#pragma unroll
  for (int it = 0; it < 8; ++it) {
    int idx = it * 256 + tid;
    int dv = idx >> 4;
    int d0 = (idx & 15) << 3;
    *reinterpret_cast<uint4*>(&vt[dv][d0]) =
        *reinterpret_cast<const uint4*>(&KVp[(size_t)c * 16384 + (size_t)dv * DHEAD + d0]);
  }
  __syncthreads();

#pragma unroll
  for (int ks = 0; ks < 4; ++ks) {
    int d0 = ks * 32 + kgrp * 8;
    bf16x8 af = *reinterpret_cast<const bf16x8*>(&qb[wave * 16 + lrow][d0]);
#pragma unroll
    for (int tc = 0; tc < 8; ++tc) {
      bf16x8 bf = *reinterpret_cast<const bf16x8*>(&vt[tc * 16 + lrow][d0]);
      acc[tc] = __builtin_amdgcn_mfma_f32_16x16x32_bf16(af, bf, acc[tc], 0, 0, 0);
    }
  }

#pragma unroll
  for (int tc = 0; tc < 8; ++tc)
#pragma unroll
    for (int r = 0; r < 4; ++r) {
      int trow = wave * 16 + kgrp * 4 + r;
      int dv = tc * 16 + lrow;
      float den = dsum[0][trow] + dsum[1][trow] + dsum[2][trow] + dsum[3][trow];
      outp[qbase + (size_t)trow * DHEAD + dv] = acc[tc][r] / den;
    }
}

extern "C" void kernel_launch(void* const* d_in, const int* in_sizes, int n_in,
                              void* d_out, int out_size, void* d_ws, size_t ws_size,
                              hipStream_t stream) {
  const float* x  = (const float*)d_in[0];
  const float* Wq = (const float*)d_in[1];
  const float* Wk = (const float*)d_in[2];
  const float* Wv = (const float*)d_in[3];
  float* out = (float*)d_out;
  char* ws = (char*)d_ws;
  unsigned short* phiQ = (unsigned short*)(ws + 0);          // 4 MB
  unsigned short* phiK = (unsigned short*)(ws + 4194304);    // 4 MB
  unsigned short* Vb   = (unsigned short*)(ws + 8388608);    // 4 MB
  unsigned short* WT   = (unsigned short*)(ws + 12582912);   // 768 KB
  float*          KVc  = (float*)(ws + 13369344);            // 8 MB
  unsigned short* KVp  = (unsigned short*)(ws + 21757952);   // 4 MB
  float*          ksc  = (float*)(ws + 25952256);            // 64 KB
  float*          ksp  = (float*)(ws + 26017792);            // 64 KB

  transpose_w_kernel<<<1536, 256, 0, stream>>>(Wq, Wk, Wv, WT);
  proj_kernel<<<dim3(256, 6), 128, 0, stream>>>(x, WT, phiQ, phiK, Vb);
  chunkkv_kernel<<<dim3(128, 2), 256, 0, stream>>>(phiK, Vb, KVc, ksc);
  prefix_kernel<<<257, 256, 0, stream>>>(KVc, ksc, KVp, ksp);
  out_kernel<<<dim3(128, 2), 256, 0, stream>>>(phiQ, phiK, Vb, KVp, ksp, out);
}